// Round 18
// baseline (62.237 us; speedup 1.0000x reference)
//
#include <hip/hip_runtime.h>

// Chamfer distance via MFMA, SINGLE-PASS dual-min, B=8, N=M=8192.
// D[i,j] = sq_i + sq_j - 2<pi,pj> as one K=16 bf16 dot (hi/lo split, fp32-class).
// Each D-tile is computed ONCE and serves BOTH outputs:
//   dist1 (rows = cloud1): rm[k] min3-accumulate over j, butterfly, part store.
//   dist2 (cols = cloud2): per-tile in-lane min3 tree over 32 regs (16 rows x
//     2 A-frags) + shfl_xor(32) half-merge -> per-wave LDS row -> block reduce
//     -> order-preserving uint atomicMin (R4-proven).
// MFMA count and B-load traffic HALVED vs the two-pass R9..R17 family, which
// was pinned at ~46us by total per-wave cycles (R16 s_nop experiment: waves
// don't hide each other's cycles in lockstep streams).
// Proven pieces: mfma4+3x s_nop (R16/R17), asm v_min3 (R17), build_a/pack (R6+).

typedef unsigned int uint;
typedef unsigned short ushort;
typedef __attribute__((ext_vector_type(8))) short short8;
typedef __attribute__((ext_vector_type(16))) float f32x16;

#define B_     8
#define N_     8192
#define M_     8192
#define BN     (B_ * N_)        // 65536
#define SPLITJ 8
#define JCH    (M_ / SPLITJ)    // 1024 cols per block sweep
#define JT     (JCH / 32)       // 32 col-tiles
#define RPW    64               // rows per wave (2 A-frags)
#define WAVES  4
#define RPB    (RPW * WAVES)    // 256 rows per block
#define RBLK   (N_ / RPB)       // 32 row-blocks per batch

// 4 MFMAs (2 A-frags x 2 B-tiles) with VGPR destinations (R16-proven).
// Trailing s_nops cover MFMA-write -> VALU-read wait states for the asm/C
// consumers that follow (hazard recognizer can't see INLINEASM uses).
__device__ __forceinline__ void mfma4(const short8 a0, const short8 a1,
                                      const short8 q0, const short8 q1,
                                      const f32x16 zc,
                                      f32x16& d00, f32x16& d01,
                                      f32x16& d10, f32x16& d11) {
    asm volatile(
        "v_mfma_f32_32x32x16_bf16 %0, %4, %6, %8\n\t"
        "v_mfma_f32_32x32x16_bf16 %1, %4, %7, %8\n\t"
        "v_mfma_f32_32x32x16_bf16 %2, %5, %6, %8\n\t"
        "v_mfma_f32_32x32x16_bf16 %3, %5, %7, %8\n\t"
        "s_nop 7\n\t"
        "s_nop 7\n\t"
        "s_nop 7"
        : "=&v"(d00), "=&v"(d01), "=&v"(d10), "=&v"(d11)
        : "v"(a0), "v"(a1), "v"(q0), "v"(q1), "v"(zc));
}

__device__ __forceinline__ float min3v(float a, float b, float c) {
    float r;
    asm("v_min3_f32 %0, %1, %2, %3" : "=v"(r) : "v"(a), "v"(b), "v"(c));
    return r;
}

// rm[k] = min3(d[k], e[k], rm[k]) — rowmin accumulate (R17-proven).
__device__ __forceinline__ void consume16(f32x16& rm, const f32x16& d, const f32x16& e) {
#pragma unroll
    for (int k = 0; k < 16; ++k) {
        float r;
        asm("v_min3_f32 %0, %2, %3, %1"
            : "=v"(r) : "v"(rm[k]), "v"(d[k]), "v"(e[k]));
        rm[k] = r;
    }
}

// colmin tree: min over the 32 regs (this lane's 16 rows of each A-frag tile).
__device__ __forceinline__ float coltree(const f32x16& d0, const f32x16& d1) {
    float t0 = min3v(d0[0],  d0[1],  d0[2]);
    float t1 = min3v(d0[3],  d0[4],  d0[5]);
    float t2 = min3v(d0[6],  d0[7],  d0[8]);
    float t3 = min3v(d0[9],  d0[10], d0[11]);
    float t4 = min3v(d0[12], d0[13], d0[14]);
    float t5 = min3v(d0[15], d1[0],  d1[1]);
    float t6 = min3v(d1[2],  d1[3],  d1[4]);
    float t7 = min3v(d1[5],  d1[6],  d1[7]);
    float t8 = min3v(d1[8],  d1[9],  d1[10]);
    float t9 = min3v(d1[11], d1[12], d1[13]);
    float u0 = min3v(t0, t1, t2);
    float u1 = min3v(t3, t4, t5);
    float u2 = min3v(t6, t7, t8);
    float u3 = min3v(t9, d1[14], d1[15]);
    return fminf(min3v(u0, u1, u2), u3);
}

__device__ __forceinline__ uint key_of(float f) {
    uint u = __float_as_uint(f);
    return (u & 0x80000000u) ? ~u : (u | 0x80000000u);
}
__device__ __forceinline__ float val_of(uint k) {
    return __uint_as_float((k & 0x80000000u) ? (k & 0x7FFFFFFFu) : ~k);
}
__device__ __forceinline__ ushort f2bf(float f) {   // RNE f32->bf16
    uint u = __float_as_uint(f);
    return (ushort)((u + 0x7FFFu + ((u >> 16) & 1u)) >> 16);
}
__device__ __forceinline__ float bf2f(ushort h) {
    return __uint_as_float(((uint)h) << 16);
}

__global__ void init_kernel(uint* __restrict__ enc) {
    int i = blockIdx.x * 256 + threadIdx.x;
    if (i < BN) enc[i] = 0xFFFFFFFFu;
}

// Col-form pack of cloud2 only (coords scaled by -2, sq unscaled). grid BN/256.
__global__ void prep_kernel(const float* __restrict__ xyz, ushort* __restrict__ vec) {
    int i = blockIdx.x * 256 + threadIdx.x;
    float x = xyz[3 * i], y = xyz[3 * i + 1], z = xyz[3 * i + 2];
    float s = fmaf(x, x, fmaf(y, y, z * z));
    x *= -2.0f; y *= -2.0f; z *= -2.0f;
    ushort xh = f2bf(x), xl = f2bf(x - bf2f(xh));
    ushort yh = f2bf(y), yl = f2bf(y - bf2f(yh));
    ushort zh = f2bf(z), zl = f2bf(z - bf2f(zh));
    ushort sh = f2bf(s), sl = f2bf(s - bf2f(sh));
    const uint one = 0x3F80u;
    uint4* dst = (uint4*)(vec + (size_t)i * 16);
    dst[0] = make_uint4((uint)xh | ((uint)xl << 16), (uint)xh | ((uint)yh << 16),
                        (uint)yl | ((uint)yh << 16), (uint)zh | ((uint)zl << 16));
    dst[1] = make_uint4((uint)zh | ((uint)sh << 16), (uint)sl | (one << 16),
                        one, 0u);
}

// Build A row-frag for global row g, k-half h, from raw xyz (cloud1).
__device__ __forceinline__ short8 build_a(const float* __restrict__ own, int g, int h) {
    float x = own[3 * g], y = own[3 * g + 1], z = own[3 * g + 2];
    float s = fmaf(x, x, fmaf(y, y, z * z));
    ushort xh = f2bf(x), xl = f2bf(x - bf2f(xh));
    ushort yh = f2bf(y), yl = f2bf(y - bf2f(yh));
    ushort zh = f2bf(z), zl = f2bf(z - bf2f(zh));
    ushort sh = f2bf(s), sl = f2bf(s - bf2f(sh));
    const ushort one = 0x3F80;
    short8 a;
    a[0] = (short)(h ? zl  : xh);
    a[1] = (short)(h ? one : xh);
    a[2] = (short)(h ? one : xl);
    a[3] = (short)(h ? sh  : yh);
    a[4] = (short)(h ? sl  : yh);
    a[5] = (short)(h ? 0   : yl);
    a[6] = (short)(h ? 0   : zh);
    a[7] = (short)(h ? 0   : zh);
    return a;
}

// grid = (B_*RBLK, SPLITJ) = (256, 8). 4 waves/block, 64 rows/wave, one pass.
__global__ __launch_bounds__(256, 2)
void cham_single(const float* __restrict__ xyz1,
                 const short8* __restrict__ Bv2,   // col-form pack of cloud2
                 float* __restrict__ part,         // [SPLITJ][BN] dist1 partials
                 uint* __restrict__ enc) {         // [BN] dist2 encoded mins
    __shared__ float cm[WAVES][JCH];               // 16 KB per-wave colmins

    const int tid  = threadIdx.x;
    const int wave = tid >> 6;
    const int lane = tid & 63;
    const int half = lane >> 5;
    const int lc   = lane & 31;

    const int b   = blockIdx.x / RBLK;
    const int rb  = blockIdx.x % RBLK;

    const int row0 = rb * RPB + wave * RPW;
    const int gr   = b * N_ + row0;

    const short8 a0 = build_a(xyz1, gr + lc, half);
    const short8 a1 = build_a(xyz1, gr + 32 + lc, half);

    f32x16 zc;
#pragma unroll
    for (int k = 0; k < 16; ++k) zc[k] = 0.0f;
    f32x16 rm0, rm1;
#pragma unroll
    for (int k = 0; k < 16; ++k) { rm0[k] = 3.0e38f; rm1[k] = 3.0e38f; }

    const short8* bp = Bv2 + ((size_t)b * M_ + (size_t)blockIdx.y * JCH + lc) * 2 + half;

    for (int t = 0; t < JT; t += 2) {
        short8 q0 = bp[t * 64];
        short8 q1 = bp[t * 64 + 64];
        f32x16 d00, d01, d10, d11;
        mfma4(a0, a1, q0, q1, zc, d00, d01, d10, d11);
        // dist1: rowmin accumulate
        consume16(rm0, d00, d01);
        consume16(rm1, d10, d11);
        // dist2: per-tile colmin (lane's 16 rows x 2 frags), merge halves
        float c0 = coltree(d00, d10);                 // tile t's 32 cols
        float c1 = coltree(d01, d11);                 // tile t+1's 32 cols
        c0 = fminf(c0, __shfl_xor(c0, 32));
        c1 = fminf(c1, __shfl_xor(c1, 32));
        cm[wave][t * 32 + lc]       = c0;             // both halves write same value
        cm[wave][(t + 1) * 32 + lc] = c1;
    }

    // dist1 finalize: butterfly min across 32 col-lanes of each half-group.
#pragma unroll
    for (int k = 0; k < 16; ++k) {
#pragma unroll
        for (int s2 = 16; s2 >= 1; s2 >>= 1) {
            rm0[k] = fminf(rm0[k], __shfl_xor(rm0[k], s2));
            rm1[k] = fminf(rm1[k], __shfl_xor(rm1[k], s2));
        }
    }
    // C layout: row = (k&3) + 8*(k>>2) + 4*half, col = lane&31.
    float* p = part + (size_t)blockIdx.y * BN + gr;
    if (lc == 0) {
#pragma unroll
        for (int k = 0; k < 16; ++k) {
            int rr = (k & 3) + 8 * (k >> 2) + 4 * half;
            p[rr]      = rm0[k];
            p[32 + rr] = rm1[k];
        }
    }

    // dist2 finalize: block-reduce the 4 waves' colmins, one atomic per col.
    __syncthreads();
    uint* e = enc + (size_t)b * M_ + (size_t)blockIdx.y * JCH;
    for (int c = tid; c < JCH; c += 256) {
        float m = fminf(fminf(cm[0][c], cm[1][c]), fminf(cm[2][c], cm[3][c]));
        atomicMin(&e[c], key_of(m));
    }
}

// dist1 = 8-way min over j-split partials; dist2 = decode enc. i in [0, 2*BN).
__global__ void decode_kernel(const float* __restrict__ part,
                              const uint* __restrict__ enc,
                              float* __restrict__ out) {
    int i = blockIdx.x * 256 + threadIdx.x;
    if (i < BN) {
        const float* p = part + i;
        float m0 = fminf(p[0],              p[(size_t)BN]);
        float m1 = fminf(p[(size_t)2 * BN], p[(size_t)3 * BN]);
        float m2 = fminf(p[(size_t)4 * BN], p[(size_t)5 * BN]);
        float m3 = fminf(p[(size_t)6 * BN], p[(size_t)7 * BN]);
        out[i] = fminf(fminf(m0, m1), fminf(m2, m3));
    } else {
        int ii = i - BN;
        out[i] = val_of(enc[ii]);
    }
}

extern "C" void kernel_launch(void* const* d_in, const int* in_sizes, int n_in,
                              void* d_out, int out_size, void* d_ws, size_t ws_size,
                              hipStream_t stream) {
    const float* xyz1 = (const float*)d_in[0];
    const float* xyz2 = (const float*)d_in[1];
    float* out = (float*)d_out;

    // ws: Bv2 (2MB) | part (SPLITJ*BN*4 = 2MB) | enc (256KB)
    ushort* Bv2 = (ushort*)d_ws;
    float*  part = (float*)(Bv2 + (size_t)BN * 16);
    uint*   enc  = (uint*)(part + (size_t)SPLITJ * BN);

    prep_kernel<<<BN / 256, 256, 0, stream>>>(xyz2, Bv2);
    init_kernel<<<BN / 256, 256, 0, stream>>>(enc);

    dim3 grid(B_ * RBLK, SPLITJ);   // (256, 8)
    cham_single<<<grid, 256, 0, stream>>>(xyz1, (const short8*)Bv2, part, enc);

    decode_kernel<<<(2 * BN) / 256, 256, 0, stream>>>(part, enc, out);
}